// Round 2
// baseline (277.641 us; speedup 1.0000x reference)
//
#include <hip/hip_runtime.h>
#include <stdint.h>

// SelfAttention: B=4, S=2048, D=1024, causal, single head of dim 1024.
// Inputs/outputs fp32 on device (per reference); GEMMs run bf16 MFMA with
// fp32 accumulation (no fp32-input MFMA on CDNA4).

typedef unsigned short u16;
typedef __attribute__((ext_vector_type(8))) short shortx8;  // 8 bf16 (4 VGPRs)
typedef __attribute__((ext_vector_type(4))) float floatx4;

static constexpr int BB = 4;
static constexpr int SS = 2048;
static constexpr int DD = 1024;

__device__ __forceinline__ u16 f2bf(float f) {
  union { float f; uint32_t u; } c; c.f = f;
  uint32_t u = c.u;
  return (u16)((u + 0x7fffu + ((u >> 16) & 1u)) >> 16);  // RNE
}

#define GLOAD_LDS16(g, l)                                                              \
  __builtin_amdgcn_global_load_lds((const __attribute__((address_space(1))) void*)(g), \
                                   (__attribute__((address_space(3))) void*)(l), 16, 0, 0)

// 128x128 C-tile GEMM core, m97 structure:
//   A  [M][lda] bf16 row-major (K contiguous), rows m0..m0+127
//   Bt [N][ldb] bf16 row-major (K contiguous), rows n0..n0+127  (i.e. B^T)
//   acc[4][4] = per-wave 4x4 grid of 16x16 fp32 tiles; waves in 2x2 arrangement.
__device__ __forceinline__ void gemm_core_128(
    const u16* __restrict__ A, const u16* __restrict__ Bt,
    int lda, int ldb, int m0, int n0, int kend, floatx4 acc[4][4])
{
  __shared__ u16 lA[128 * 32];  // [row=m][col=k], 64B rows
  __shared__ u16 lB[128 * 32];  // [row=n][col=k]
  const int t = threadIdx.x;
  const int w = t >> 6, l = t & 63;
  const int wm = w >> 1, wn = w & 1;
  const int sr = l >> 2;        // staging: lane -> row within 16-row chunk
  const int sc = (l & 3) * 8;   // staging: lane -> 8-elem (16B) col chunk

#pragma unroll
  for (int i = 0; i < 4; ++i)
#pragma unroll
    for (int j = 0; j < 4; ++j)
      acc[i][j] = (floatx4){0.f, 0.f, 0.f, 0.f};

  const u16* Ab = A + (size_t)m0 * lda;
  const u16* Bb = Bt + (size_t)n0 * ldb;

  for (int k0 = 0; k0 < kend; k0 += 32) {
    // stage A/B tiles: each wave stages 2x16 rows of each; lds dst is
    // wave-uniform base, HW scatters lane*16B (layout matches source order).
#pragma unroll
    for (int i = 0; i < 2; ++i) {
      const int row = w * 32 + i * 16;
      GLOAD_LDS16(Ab + (size_t)(row + sr) * lda + k0 + sc, &lA[row * 32]);
      GLOAD_LDS16(Bb + (size_t)(row + sr) * ldb + k0 + sc, &lB[row * 32]);
    }
    __syncthreads();  // drains vmcnt before barrier -> LDS visible

    shortx8 af[4], bf[4];
#pragma unroll
    for (int i = 0; i < 4; ++i)  // A frag: A[m=lane&15][k=quad*8+j]
      af[i] = *(const shortx8*)&lA[(wm * 64 + i * 16 + (l & 15)) * 32 + (l >> 4) * 8];
#pragma unroll
    for (int i = 0; i < 4; ++i)  // B frag: B^T[n=lane&15][k=quad*8+j]
      bf[i] = *(const shortx8*)&lB[(wn * 64 + i * 16 + (l & 15)) * 32 + (l >> 4) * 8];
#pragma unroll
    for (int i = 0; i < 4; ++i)
#pragma unroll
      for (int j = 0; j < 4; ++j)
        acc[i][j] = __builtin_amdgcn_mfma_f32_16x16x32_bf16(af[i], bf[j], acc[i][j], 0, 0, 0);
    __syncthreads();  // protect LDS before next stage
  }
}

// ---- kernel 0: xb = bf16(x), vectorized ----
__global__ __launch_bounds__(256) void x_convert(const float* __restrict__ x,
                                                 u16* __restrict__ xb) {
  const size_t i = (size_t)blockIdx.x * 256 + threadIdx.x;  // float4 index
  float4 v = ((const float4*)x)[i];
  ushort4 o;
  o.x = f2bf(v.x); o.y = f2bf(v.y); o.z = f2bf(v.z); o.w = f2bf(v.w);
  ((ushort4*)xb)[i] = o;
}

// ---- kernel 1: Wt[n][k] = bf16(W{q|k|v}[k][n]), 3072x1024 ----
__global__ __launch_bounds__(256) void wt_build(const float* __restrict__ WQ,
                                                const float* __restrict__ WK,
                                                const float* __restrict__ WV,
                                                u16* __restrict__ Wt) {
  __shared__ float tile[64][65];
  const int wsel = blockIdx.z;
  const float* W = wsel == 0 ? WQ : (wsel == 1 ? WK : WV);
  const int k0 = blockIdx.y * 64, n0 = blockIdx.x * 64;
  const int tx = threadIdx.x, ty = threadIdx.y;  // (64,4)
#pragma unroll
  for (int i = 0; i < 16; ++i)
    tile[ty + i * 4][tx] = W[(size_t)(k0 + ty + i * 4) * DD + n0 + tx];
  __syncthreads();
  u16* dst = Wt + (size_t)wsel * DD * DD;
#pragma unroll
  for (int i = 0; i < 16; ++i)
    dst[(size_t)(n0 + ty + i * 4) * DD + k0 + tx] = f2bf(tile[tx][ty + i * 4]);
}

// ---- kernel 2: fused QKV projection, M=8192 N=3072 K=1024, bf16 out ----
__global__ __launch_bounds__(256, 2) void qkv_gemm(const u16* __restrict__ x,
                                                   const u16* __restrict__ Wt,
                                                   u16* __restrict__ Q,
                                                   u16* __restrict__ K,
                                                   u16* __restrict__ V) {
  const int m0 = blockIdx.x * 128;
  const int n0t = blockIdx.y * 128;
  floatx4 acc[4][4];
  gemm_core_128(x, Wt, DD, DD, m0, n0t, DD, acc);

  u16* out;
  int n0;
  if (n0t < 1024)      { out = Q; n0 = n0t; }
  else if (n0t < 2048) { out = K; n0 = n0t - 1024; }
  else                 { out = V; n0 = n0t - 2048; }

  const int t = threadIdx.x, w = t >> 6, l = t & 63;
  const int wm = w >> 1, wn = w & 1;
#pragma unroll
  for (int i = 0; i < 4; ++i)
#pragma unroll
    for (int j = 0; j < 4; ++j)
#pragma unroll
      for (int r = 0; r < 4; ++r) {
        const int m = m0 + wm * 64 + i * 16 + (l >> 4) * 4 + r;
        const int n = n0 + wn * 64 + j * 16 + (l & 15);
        out[(size_t)m * DD + n] = f2bf(acc[i][j][r]);
      }
}

// ---- kernel 3: Vt[b][d][s] = V[b][s][d], bf16 ----
__global__ __launch_bounds__(256) void v_transpose(const u16* __restrict__ V,
                                                   u16* __restrict__ Vt) {
  __shared__ u16 tile[64][65];
  const int b = blockIdx.z;
  const int r0 = blockIdx.y * 64, c0 = blockIdx.x * 64;
  const u16* src = V + (size_t)b * SS * DD;
  u16* dst = Vt + (size_t)b * DD * SS;
  const int tx = threadIdx.x, ty = threadIdx.y;
#pragma unroll
  for (int i = 0; i < 16; ++i)
    tile[ty + i * 4][tx] = src[(size_t)(r0 + ty + i * 4) * DD + c0 + tx];
  __syncthreads();
#pragma unroll
  for (int i = 0; i < 16; ++i)
    dst[(size_t)(c0 + ty + i * 4) * SS + r0 + tx] = tile[tx][ty + i * 4];
}

// ---- kernel 4: Sc = Q K^T / 32 fp32, lower-triangular blocks only ----
__global__ __launch_bounds__(256, 2) void scores_gemm(const u16* __restrict__ Q,
                                                      const u16* __restrict__ Kt,
                                                      float* __restrict__ Sc) {
  const int b = blockIdx.z;
  const int m0 = blockIdx.y * 128, n0 = blockIdx.x * 128;
  if (m0 < n0) return;  // strictly-upper block: never read downstream
  floatx4 acc[4][4];
  gemm_core_128(Q + (size_t)b * SS * DD, Kt + (size_t)b * SS * DD, DD, DD, m0, n0, DD, acc);

  float* out = Sc + (size_t)b * SS * SS;
  const int t = threadIdx.x, w = t >> 6, l = t & 63;
  const int wm = w >> 1, wn = w & 1;
#pragma unroll
  for (int i = 0; i < 4; ++i)
#pragma unroll
    for (int j = 0; j < 4; ++j)
#pragma unroll
      for (int r = 0; r < 4; ++r) {
        const int m = m0 + wm * 64 + i * 16 + (l >> 4) * 4 + r;
        const int n = n0 + wn * 64 + j * 16 + (l & 15);
        out[(size_t)m * SS + n] = acc[i][j][r] * 0.03125f;  // 1/sqrt(1024)
      }
}

// ---- kernel 5: causal row softmax, Sc fp32 -> P bf16, zero-fill to block edge ----
__global__ __launch_bounds__(256) void softmax_causal(const float* __restrict__ Sc,
                                                      u16* __restrict__ P) {
  const int row = blockIdx.x;  // b*2048 + i
  const int b = row >> 11, i = row & 2047;
  const float* s = Sc + (size_t)b * SS * SS + (size_t)i * SS;
  u16* p = P + (size_t)b * SS * SS + (size_t)i * SS;
  const int t = threadIdx.x;
  const int n = i + 1;                   // valid columns [0, n)
  const int jend = (i + 128) & ~127;     // 128-aligned diag-block edge (PV reads to here)

  __shared__ float red[4];

  float mx = -INFINITY;
  for (int j = t; j < n; j += 256) mx = fmaxf(mx, s[j]);
#pragma unroll
  for (int o = 32; o > 0; o >>= 1) mx = fmaxf(mx, __shfl_down(mx, o, 64));
  if ((t & 63) == 0) red[t >> 6] = mx;
  __syncthreads();
  mx = fmaxf(fmaxf(red[0], red[1]), fmaxf(red[2], red[3]));

  float sum = 0.f;
  for (int j = t; j < n; j += 256) sum += __expf(s[j] - mx);
#pragma unroll
  for (int o = 32; o > 0; o >>= 1) sum += __shfl_down(sum, o, 64);
  __syncthreads();  // red reuse
  if ((t & 63) == 0) red[t >> 6] = sum;
  __syncthreads();
  sum = red[0] + red[1] + red[2] + red[3];
  const float inv = 1.0f / sum;

  for (int j = t; j < n; j += 256) p[j] = f2bf(__expf(s[j] - mx) * inv);
  for (int j = n + t; j < jend; j += 256) p[j] = 0;
}

// ---- kernel 6: O = P V (causal K-range), fp32 out ----
__global__ __launch_bounds__(256, 2) void pv_gemm(const u16* __restrict__ P,
                                                  const u16* __restrict__ Vt,
                                                  float* __restrict__ out) {
  const int b = blockIdx.z;
  const int m0 = blockIdx.y * 128, n0 = blockIdx.x * 128;
  floatx4 acc[4][4];
  // rows m0..m0+127 only attend to keys k < m0+128
  gemm_core_128(P + (size_t)b * SS * SS, Vt + (size_t)b * DD * SS, SS, SS, m0, n0, m0 + 128, acc);

  float* o = out + (size_t)b * SS * DD;
  const int t = threadIdx.x, w = t >> 6, l = t & 63;
  const int wm = w >> 1, wn = w & 1;
#pragma unroll
  for (int i = 0; i < 4; ++i)
#pragma unroll
    for (int j = 0; j < 4; ++j)
#pragma unroll
      for (int r = 0; r < 4; ++r) {
        const int m = m0 + wm * 64 + i * 16 + (l >> 4) * 4 + r;
        const int n = n0 + wn * 64 + j * 16 + (l & 15);
        o[(size_t)m * DD + n] = acc[i][j][r];
      }
}

extern "C" void kernel_launch(void* const* d_in, const int* in_sizes, int n_in,
                              void* d_out, int out_size, void* d_ws, size_t ws_size,
                              hipStream_t stream) {
  const float* x  = (const float*)d_in[0];
  const float* WQ = (const float*)d_in[1];
  const float* WK = (const float*)d_in[2];
  const float* WV = (const float*)d_in[3];
  float* out = (float*)d_out;

  // workspace carve (bytes): Wt 6M | xb 16M | Q 16M | K 16M | V 16M | Vt 16M | P 32M | Sc 64M
  char* ws = (char*)d_ws;
  const size_t WT_OFF = 0;
  const size_t XB_OFF = WT_OFF + (size_t)3072 * 1024 * 2;
  const size_t Q_OFF  = XB_OFF + (size_t)BB * SS * DD * 2;
  const size_t K_OFF  = Q_OFF + (size_t)BB * SS * DD * 2;
  const size_t V_OFF  = K_OFF + (size_t)BB * SS * DD * 2;
  const size_t VT_OFF = V_OFF + (size_t)BB * SS * DD * 2;
  const size_t P_OFF  = VT_OFF + (size_t)BB * SS * DD * 2;
  const size_t SC_OFF = P_OFF + (size_t)BB * SS * SS * 2;
  u16*   Wt = (u16*)(ws + WT_OFF);
  u16*   xb = (u16*)(ws + XB_OFF);
  u16*   Q  = (u16*)(ws + Q_OFF);
  u16*   Kb = (u16*)(ws + K_OFF);
  u16*   V  = (u16*)(ws + V_OFF);
  u16*   Vt = (u16*)(ws + VT_OFF);
  u16*   P  = (u16*)(ws + P_OFF);
  float* Sc = (float*)(ws + SC_OFF);

  hipLaunchKernelGGL(x_convert, dim3(8192), dim3(256), 0, stream, x, xb);
  hipLaunchKernelGGL(wt_build, dim3(16, 16, 3), dim3(64, 4), 0, stream, WQ, WK, WV, Wt);
  hipLaunchKernelGGL(qkv_gemm, dim3(64, 24), dim3(256), 0, stream, xb, Wt, Q, Kb, V);
  hipLaunchKernelGGL(v_transpose, dim3(16, 32, 4), dim3(64, 4), 0, stream, V, Vt);
  hipLaunchKernelGGL(scores_gemm, dim3(16, 16, 4), dim3(256), 0, stream, Q, Kb, Sc);
  hipLaunchKernelGGL(softmax_causal, dim3(8192), dim3(256), 0, stream, Sc, P);
  hipLaunchKernelGGL(pv_gemm, dim3(8, 16, 4), dim3(256), 0, stream, P, Vt, out);
}

// Round 3
// 262.957 us; speedup vs baseline: 1.0558x; 1.0558x over previous
//
#include <hip/hip_runtime.h>
#include <stdint.h>

// SelfAttention: B=4, S=2048, D=1024, causal, single head of dim 1024.
// Inputs/outputs fp32 on device (per reference); GEMMs run bf16 MFMA with
// fp32 accumulation (no fp32-input MFMA on CDNA4).

typedef unsigned short u16;
typedef __attribute__((ext_vector_type(8))) short shortx8;  // 8 bf16 (4 VGPRs)
typedef __attribute__((ext_vector_type(4))) float floatx4;

static constexpr int BB = 4;
static constexpr int SS = 2048;
static constexpr int DD = 1024;

__device__ __forceinline__ u16 f2bf(float f) {
  union { float f; uint32_t u; } c; c.f = f;
  uint32_t u = c.u;
  return (u16)((u + 0x7fffu + ((u >> 16) & 1u)) >> 16);  // RNE
}

#define GLOAD_LDS16(g, l)                                                              \
  __builtin_amdgcn_global_load_lds((const __attribute__((address_space(1))) void*)(g), \
                                   (__attribute__((address_space(3))) void*)(l), 16, 0, 0)

// 128x128 C-tile GEMM core, m97 structure:
//   A  [M][lda] bf16 row-major (K contiguous), rows m0..m0+127
//   Bt [N][ldb] bf16 row-major (K contiguous), rows n0..n0+127  (i.e. B^T)
//   acc[4][4] = per-wave 4x4 grid of 16x16 fp32 tiles; waves in 2x2 arrangement.
__device__ __forceinline__ void gemm_core_128(
    const u16* __restrict__ A, const u16* __restrict__ Bt,
    int lda, int ldb, int m0, int n0, int kend, floatx4 acc[4][4])
{
  __shared__ u16 lA[128 * 32];  // [row=m][col=k], 64B rows
  __shared__ u16 lB[128 * 32];  // [row=n][col=k]
  const int t = threadIdx.x;
  const int w = t >> 6, l = t & 63;
  const int wm = w >> 1, wn = w & 1;
  const int sr = l >> 2;        // staging: lane -> row within 16-row chunk
  const int sc = (l & 3) * 8;   // staging: lane -> 8-elem (16B) col chunk

#pragma unroll
  for (int i = 0; i < 4; ++i)
#pragma unroll
    for (int j = 0; j < 4; ++j)
      acc[i][j] = (floatx4){0.f, 0.f, 0.f, 0.f};

  const u16* Ab = A + (size_t)m0 * lda;
  const u16* Bb = Bt + (size_t)n0 * ldb;

  for (int k0 = 0; k0 < kend; k0 += 32) {
    // stage A/B tiles: each wave stages 2x16 rows of each; lds dst is
    // wave-uniform base, HW scatters lane*16B (layout matches source order).
#pragma unroll
    for (int i = 0; i < 2; ++i) {
      const int row = w * 32 + i * 16;
      GLOAD_LDS16(Ab + (size_t)(row + sr) * lda + k0 + sc, &lA[row * 32]);
      GLOAD_LDS16(Bb + (size_t)(row + sr) * ldb + k0 + sc, &lB[row * 32]);
    }
    __syncthreads();  // drains vmcnt before barrier -> LDS visible

    shortx8 af[4], bf[4];
#pragma unroll
    for (int i = 0; i < 4; ++i)  // A frag: A[m=lane&15][k=quad*8+j]
      af[i] = *(const shortx8*)&lA[(wm * 64 + i * 16 + (l & 15)) * 32 + (l >> 4) * 8];
#pragma unroll
    for (int i = 0; i < 4; ++i)  // B frag: B^T[n=lane&15][k=quad*8+j]
      bf[i] = *(const shortx8*)&lB[(wn * 64 + i * 16 + (l & 15)) * 32 + (l >> 4) * 8];
#pragma unroll
    for (int i = 0; i < 4; ++i)
#pragma unroll
      for (int j = 0; j < 4; ++j)
        acc[i][j] = __builtin_amdgcn_mfma_f32_16x16x32_bf16(af[i], bf[j], acc[i][j], 0, 0, 0);
    __syncthreads();  // protect LDS before next stage
  }
}

// ---- kernel 0: xb = bf16(x), vectorized ----
__global__ __launch_bounds__(256) void x_convert(const float* __restrict__ x,
                                                 u16* __restrict__ xb) {
  const size_t i = (size_t)blockIdx.x * 256 + threadIdx.x;  // float4 index
  float4 v = ((const float4*)x)[i];
  ushort4 o;
  o.x = f2bf(v.x); o.y = f2bf(v.y); o.z = f2bf(v.z); o.w = f2bf(v.w);
  ((ushort4*)xb)[i] = o;
}

// ---- kernel 1: Wt[n][k] = bf16(W{q|k|v}[k][n]), 3072x1024 ----
__global__ __launch_bounds__(256) void wt_build(const float* __restrict__ WQ,
                                                const float* __restrict__ WK,
                                                const float* __restrict__ WV,
                                                u16* __restrict__ Wt) {
  __shared__ float tile[64][65];
  const int wsel = blockIdx.z;
  const float* W = wsel == 0 ? WQ : (wsel == 1 ? WK : WV);
  const int k0 = blockIdx.y * 64, n0 = blockIdx.x * 64;
  const int tx = threadIdx.x, ty = threadIdx.y;  // (64,4)
#pragma unroll
  for (int i = 0; i < 16; ++i)
    tile[ty + i * 4][tx] = W[(size_t)(k0 + ty + i * 4) * DD + n0 + tx];
  __syncthreads();
  u16* dst = Wt + (size_t)wsel * DD * DD;
#pragma unroll
  for (int i = 0; i < 16; ++i)
    dst[(size_t)(n0 + ty + i * 4) * DD + k0 + tx] = f2bf(tile[tx][ty + i * 4]);
}

// ---- kernel 2: fused QKV projection, M=8192 N=3072 K=1024, bf16 out ----
__global__ __launch_bounds__(256, 2) void qkv_gemm(const u16* __restrict__ x,
                                                   const u16* __restrict__ Wt,
                                                   u16* __restrict__ Q,
                                                   u16* __restrict__ K,
                                                   u16* __restrict__ V) {
  const int m0 = blockIdx.x * 128;
  const int n0t = blockIdx.y * 128;
  floatx4 acc[4][4];
  gemm_core_128(x, Wt, DD, DD, m0, n0t, DD, acc);

  u16* out;
  int n0;
  if (n0t < 1024)      { out = Q; n0 = n0t; }
  else if (n0t < 2048) { out = K; n0 = n0t - 1024; }
  else                 { out = V; n0 = n0t - 2048; }

  const int t = threadIdx.x, w = t >> 6, l = t & 63;
  const int wm = w >> 1, wn = w & 1;
#pragma unroll
  for (int i = 0; i < 4; ++i)
#pragma unroll
    for (int j = 0; j < 4; ++j)
#pragma unroll
      for (int r = 0; r < 4; ++r) {
        const int m = m0 + wm * 64 + i * 16 + (l >> 4) * 4 + r;
        const int n = n0 + wn * 64 + j * 16 + (l & 15);
        out[(size_t)m * DD + n] = f2bf(acc[i][j][r]);
      }
}

// ---- kernel 3: Vt[b][d][s] = V[b][s][d], bf16 ----
__global__ __launch_bounds__(256) void v_transpose(const u16* __restrict__ V,
                                                   u16* __restrict__ Vt) {
  __shared__ u16 tile[64][65];
  const int b = blockIdx.z;
  const int r0 = blockIdx.y * 64, c0 = blockIdx.x * 64;
  const u16* src = V + (size_t)b * SS * DD;
  u16* dst = Vt + (size_t)b * DD * SS;
  const int tx = threadIdx.x, ty = threadIdx.y;
#pragma unroll
  for (int i = 0; i < 16; ++i)
    tile[ty + i * 4][tx] = src[(size_t)(r0 + ty + i * 4) * DD + c0 + tx];
  __syncthreads();
#pragma unroll
  for (int i = 0; i < 16; ++i)
    dst[(size_t)(c0 + ty + i * 4) * SS + r0 + tx] = tile[tx][ty + i * 4];
}

// ---- kernel 4: Sc = Q K^T / 32 fp32, lower-triangular blocks only,
//      triangular-packed grid: blockIdx.x in [0,136) decodes to (mb,nb) ----
__global__ __launch_bounds__(256, 2) void scores_gemm(const u16* __restrict__ Q,
                                                      const u16* __restrict__ Kt,
                                                      float* __restrict__ Sc) {
  const int b = blockIdx.z;
  const int tcode = blockIdx.x;  // 0..135
  int mb = (int)((sqrtf(8.0f * (float)tcode + 1.0f) - 1.0f) * 0.5f);
  while ((mb + 1) * (mb + 2) / 2 <= tcode) ++mb;  // fixup fp error
  while (mb * (mb + 1) / 2 > tcode) --mb;
  const int nb = tcode - mb * (mb + 1) / 2;
  const int m0 = mb * 128, n0 = nb * 128;

  floatx4 acc[4][4];
  gemm_core_128(Q + (size_t)b * SS * DD, Kt + (size_t)b * SS * DD, DD, DD, m0, n0, DD, acc);

  float* out = Sc + (size_t)b * SS * SS;
  const int t = threadIdx.x, w = t >> 6, l = t & 63;
  const int wm = w >> 1, wn = w & 1;
#pragma unroll
  for (int i = 0; i < 4; ++i)
#pragma unroll
    for (int j = 0; j < 4; ++j)
#pragma unroll
      for (int r = 0; r < 4; ++r) {
        const int m = m0 + wm * 64 + i * 16 + (l >> 4) * 4 + r;
        const int n = n0 + wn * 64 + j * 16 + (l & 15);
        out[(size_t)m * SS + n] = acc[i][j][r] * 0.03125f;  // 1/sqrt(1024)
      }
}

// ---- kernel 5: causal row softmax, one WAVE per row, register-cached.
//      Single global read; no LDS, no block barriers. P bf16 out, rows
//      zero-filled through the 128-aligned diag-block edge. ----
__global__ __launch_bounds__(256) void softmax_causal(const float* __restrict__ Sc,
                                                      u16* __restrict__ P) {
  const int row = blockIdx.x * 4 + (threadIdx.x >> 6);  // b*2048 + i
  const int l = threadIdx.x & 63;
  const int b = row >> 11, i = row & 2047;
  const float* s = Sc + (size_t)b * SS * SS + (size_t)i * SS;
  u16* p = P + (size_t)b * SS * SS + (size_t)i * SS;
  const int n = i + 1;                      // valid columns [0, n)
  const int jend = (i + 128) & ~127;        // pv reads cols [0, jend)
  const int nc = (jend + 255) >> 8;         // 256-col chunks (1..8)

  float4 v[8];
  float mx = -INFINITY;
#pragma unroll
  for (int c = 0; c < 8; ++c) {
    if (c < nc) {
      const int col = (c * 64 + l) * 4;
      float4 a = *(const float4*)(s + col);
      a.x = (col + 0 < n) ? a.x : -INFINITY;
      a.y = (col + 1 < n) ? a.y : -INFINITY;
      a.z = (col + 2 < n) ? a.z : -INFINITY;
      a.w = (col + 3 < n) ? a.w : -INFINITY;
      v[c] = a;
      mx = fmaxf(mx, fmaxf(fmaxf(a.x, a.y), fmaxf(a.z, a.w)));
    }
  }
#pragma unroll
  for (int o = 32; o > 0; o >>= 1) mx = fmaxf(mx, __shfl_xor(mx, o, 64));

  float sum = 0.f;
#pragma unroll
  for (int c = 0; c < 8; ++c) {
    if (c < nc) {
      float4 a = v[c];
      a.x = __expf(a.x - mx);  // exp(-inf)=0 for masked lanes
      a.y = __expf(a.y - mx);
      a.z = __expf(a.z - mx);
      a.w = __expf(a.w - mx);
      v[c] = a;
      sum += (a.x + a.y) + (a.z + a.w);
    }
  }
#pragma unroll
  for (int o = 32; o > 0; o >>= 1) sum += __shfl_xor(sum, o, 64);
  const float inv = 1.0f / sum;

#pragma unroll
  for (int c = 0; c < 8; ++c) {
    if (c < nc) {
      const int col = (c * 64 + l) * 4;
      ushort4 o4;
      o4.x = f2bf(v[c].x * inv);
      o4.y = f2bf(v[c].y * inv);
      o4.z = f2bf(v[c].z * inv);
      o4.w = f2bf(v[c].w * inv);
      *(ushort4*)(p + col) = o4;
    }
  }
}

// ---- kernel 6: O = P V (causal K-range), fp32 out; longest blocks first ----
__global__ __launch_bounds__(256, 2) void pv_gemm(const u16* __restrict__ P,
                                                  const u16* __restrict__ Vt,
                                                  float* __restrict__ out) {
  const int b = blockIdx.z;
  const int mb = 15 - blockIdx.y;           // schedule kend=2048 blocks first
  const int m0 = mb * 128, n0 = blockIdx.x * 128;
  floatx4 acc[4][4];
  // rows m0..m0+127 only attend to keys k < m0+128
  gemm_core_128(P + (size_t)b * SS * SS, Vt + (size_t)b * DD * SS, SS, SS, m0, n0, m0 + 128, acc);

  float* o = out + (size_t)b * SS * DD;
  const int t = threadIdx.x, w = t >> 6, l = t & 63;
  const int wm = w >> 1, wn = w & 1;
#pragma unroll
  for (int i = 0; i < 4; ++i)
#pragma unroll
    for (int j = 0; j < 4; ++j)
#pragma unroll
      for (int r = 0; r < 4; ++r) {
        const int m = m0 + wm * 64 + i * 16 + (l >> 4) * 4 + r;
        const int n = n0 + wn * 64 + j * 16 + (l & 15);
        o[(size_t)m * DD + n] = acc[i][j][r];
      }
}

extern "C" void kernel_launch(void* const* d_in, const int* in_sizes, int n_in,
                              void* d_out, int out_size, void* d_ws, size_t ws_size,
                              hipStream_t stream) {
  const float* x  = (const float*)d_in[0];
  const float* WQ = (const float*)d_in[1];
  const float* WK = (const float*)d_in[2];
  const float* WV = (const float*)d_in[3];
  float* out = (float*)d_out;

  // workspace carve (bytes): Wt 6M | xb 16M | Q 16M | K 16M | V 16M | Vt 16M | P 32M | Sc 64M
  char* ws = (char*)d_ws;
  const size_t WT_OFF = 0;
  const size_t XB_OFF = WT_OFF + (size_t)3072 * 1024 * 2;
  const size_t Q_OFF  = XB_OFF + (size_t)BB * SS * DD * 2;
  const size_t K_OFF  = Q_OFF + (size_t)BB * SS * DD * 2;
  const size_t V_OFF  = K_OFF + (size_t)BB * SS * DD * 2;
  const size_t VT_OFF = V_OFF + (size_t)BB * SS * DD * 2;
  const size_t P_OFF  = VT_OFF + (size_t)BB * SS * DD * 2;
  const size_t SC_OFF = P_OFF + (size_t)BB * SS * SS * 2;
  u16*   Wt = (u16*)(ws + WT_OFF);
  u16*   xb = (u16*)(ws + XB_OFF);
  u16*   Q  = (u16*)(ws + Q_OFF);
  u16*   Kb = (u16*)(ws + K_OFF);
  u16*   V  = (u16*)(ws + V_OFF);
  u16*   Vt = (u16*)(ws + VT_OFF);
  u16*   P  = (u16*)(ws + P_OFF);
  float* Sc = (float*)(ws + SC_OFF);

  hipLaunchKernelGGL(x_convert, dim3(8192), dim3(256), 0, stream, x, xb);
  hipLaunchKernelGGL(wt_build, dim3(16, 16, 3), dim3(64, 4), 0, stream, WQ, WK, WV, Wt);
  hipLaunchKernelGGL(qkv_gemm, dim3(64, 24), dim3(256), 0, stream, xb, Wt, Q, Kb, V);
  hipLaunchKernelGGL(v_transpose, dim3(16, 32, 4), dim3(64, 4), 0, stream, V, Vt);
  hipLaunchKernelGGL(scores_gemm, dim3(136, 1, 4), dim3(256), 0, stream, Q, Kb, Sc);
  hipLaunchKernelGGL(softmax_causal, dim3(2048), dim3(256), 0, stream, Sc, P);
  hipLaunchKernelGGL(pv_gemm, dim3(8, 16, 4), dim3(256), 0, stream, P, Vt, out);
}

// Round 4
// 262.829 us; speedup vs baseline: 1.0564x; 1.0005x over previous
//
#include <hip/hip_runtime.h>
#include <stdint.h>

// SelfAttention: B=4, S=2048, D=1024, causal, single head of dim 1024.
// Inputs/outputs fp32 on device (per reference); GEMMs run bf16 MFMA with
// fp32 accumulation (no fp32-input MFMA on CDNA4).

typedef unsigned short u16;
typedef __attribute__((ext_vector_type(8))) short shortx8;  // 8 bf16 (4 VGPRs)
typedef __attribute__((ext_vector_type(4))) float floatx4;

static constexpr int BB = 4;
static constexpr int SS = 2048;
static constexpr int DD = 1024;

__device__ __forceinline__ u16 f2bf(float f) {
  union { float f; uint32_t u; } c; c.f = f;
  uint32_t u = c.u;
  return (u16)((u + 0x7fffu + ((u >> 16) & 1u)) >> 16);  // RNE
}

#define GLOAD_LDS16(g, l)                                                              \
  __builtin_amdgcn_global_load_lds((const __attribute__((address_space(1))) void*)(g), \
                                   (__attribute__((address_space(3))) void*)(l), 16, 0, 0)

// 128x128 C-tile GEMM core, BK=64 (half the barrier drains vs BK=32):
//   A  [M][lda] bf16 row-major (K contiguous), rows m0..m0+127
//   Bt [N][ldb] bf16 row-major (K contiguous), rows n0..n0+127  (i.e. B^T)
//   acc[4][4] = per-wave 4x4 grid of 16x16 fp32 tiles; waves in 2x2 arrangement.
//   kend must be a multiple of 64.
__device__ __forceinline__ void gemm_core_128(
    const u16* __restrict__ A, const u16* __restrict__ Bt,
    int lda, int ldb, int m0, int n0, int kend, floatx4 acc[4][4])
{
  __shared__ u16 lA[128 * 64];  // [row=m][col=k], 128B rows
  __shared__ u16 lB[128 * 64];  // [row=n][col=k]
  const int t = threadIdx.x;
  const int w = t >> 6, l = t & 63;
  const int wm = w >> 1, wn = w & 1;
  const int sr = l >> 3;        // staging: lane -> row within 8-row chunk
  const int sc = (l & 7) * 8;   // staging: lane -> 8-elem (16B) col chunk

#pragma unroll
  for (int i = 0; i < 4; ++i)
#pragma unroll
    for (int j = 0; j < 4; ++j)
      acc[i][j] = (floatx4){0.f, 0.f, 0.f, 0.f};

  const u16* Ab = A + (size_t)m0 * lda;
  const u16* Bb = Bt + (size_t)n0 * ldb;

  for (int k0 = 0; k0 < kend; k0 += 64) {
    // stage A/B 128x64 tiles: each wave stages 4x8 rows of each.
#pragma unroll
    for (int i = 0; i < 4; ++i) {
      const int row = w * 32 + i * 8;
      GLOAD_LDS16(Ab + (size_t)(row + sr) * lda + k0 + sc, &lA[row * 64]);
      GLOAD_LDS16(Bb + (size_t)(row + sr) * ldb + k0 + sc, &lB[row * 64]);
    }
    __syncthreads();  // drains vmcnt before barrier -> LDS visible

#pragma unroll
    for (int ks = 0; ks < 2; ++ks) {
      shortx8 af[4], bf[4];
#pragma unroll
      for (int i = 0; i < 4; ++i)  // A frag: A[m=lane&15][k=quad*8+j]
        af[i] = *(const shortx8*)&lA[(wm * 64 + i * 16 + (l & 15)) * 64 + ks * 32 + (l >> 4) * 8];
#pragma unroll
      for (int i = 0; i < 4; ++i)  // B frag: B^T[n=lane&15][k=quad*8+j]
        bf[i] = *(const shortx8*)&lB[(wn * 64 + i * 16 + (l & 15)) * 64 + ks * 32 + (l >> 4) * 8];
#pragma unroll
      for (int i = 0; i < 4; ++i)
#pragma unroll
        for (int j = 0; j < 4; ++j)
          acc[i][j] = __builtin_amdgcn_mfma_f32_16x16x32_bf16(af[i], bf[j], acc[i][j], 0, 0, 0);
    }
    __syncthreads();  // protect LDS before next stage
  }
}

// ---- kernel 0: prep = x_convert (blocks 0..8191) + wt_build (blocks 8192..8959) ----
__global__ __launch_bounds__(256) void prep(const float* __restrict__ x,
                                            const float* __restrict__ WQ,
                                            const float* __restrict__ WK,
                                            const float* __restrict__ WV,
                                            u16* __restrict__ xb,
                                            u16* __restrict__ Wt) {
  __shared__ float tile[64][65];
  const int bid = blockIdx.x;
  const int t = threadIdx.x;
  if (bid < 8192) {  // xb = bf16(x), float4-vectorized
    const size_t i = (size_t)bid * 256 + t;
    float4 v = ((const float4*)x)[i];
    ushort4 o;
    o.x = f2bf(v.x); o.y = f2bf(v.y); o.z = f2bf(v.z); o.w = f2bf(v.w);
    ((ushort4*)xb)[i] = o;
    return;
  }
  // Wt[n][k] = bf16(W[k][n]), 64x64 tiles through LDS
  const int r = bid - 8192;      // 0..767
  const int wsel = r >> 8;       // 0..2
  const int rr = r & 255;
  const int k0 = (rr >> 4) * 64, n0 = (rr & 15) * 64;
  const float* W = wsel == 0 ? WQ : (wsel == 1 ? WK : WV);
  const int tx = t & 63, ty = t >> 6;
#pragma unroll
  for (int i = 0; i < 16; ++i)
    tile[ty + i * 4][tx] = W[(size_t)(k0 + ty + i * 4) * DD + n0 + tx];
  __syncthreads();
  u16* dst = Wt + (size_t)wsel * DD * DD;
#pragma unroll
  for (int i = 0; i < 16; ++i)
    dst[(size_t)(n0 + ty + i * 4) * DD + k0 + tx] = f2bf(tile[tx][ty + i * 4]);
}

// ---- kernel 1: fused QKV projection, M=8192 N=3072 K=1024.
//      Q,K written row-major bf16; V written TRANSPOSED into Vt[b][d][s]. ----
__global__ __launch_bounds__(256, 2) void qkv_gemm(const u16* __restrict__ x,
                                                   const u16* __restrict__ Wt,
                                                   u16* __restrict__ Q,
                                                   u16* __restrict__ K,
                                                   u16* __restrict__ Vt) {
  const int m0 = blockIdx.x * 128;
  const int n0t = blockIdx.y * 128;
  floatx4 acc[4][4];
  gemm_core_128(x, Wt, DD, DD, m0, n0t, DD, acc);

  const int t = threadIdx.x, w = t >> 6, l = t & 63;
  const int wm = w >> 1, wn = w & 1;

  if (n0t >= 2048) {  // V tile: write transposed. Each lane: 4 contiguous s per (i,j).
    const int bb = m0 >> 11;
    const int s0 = (m0 & 2047) + wm * 64 + (l >> 4) * 4;
    u16* vt = Vt + (size_t)bb * DD * SS;
#pragma unroll
    for (int i = 0; i < 4; ++i)
#pragma unroll
      for (int j = 0; j < 4; ++j) {
        const int n = (n0t - 2048) + wn * 64 + j * 16 + (l & 15);
        const int s = s0 + i * 16;
        ushort4 o4;
        o4.x = f2bf(acc[i][j][0]);
        o4.y = f2bf(acc[i][j][1]);
        o4.z = f2bf(acc[i][j][2]);
        o4.w = f2bf(acc[i][j][3]);
        *(ushort4*)(vt + (size_t)n * SS + s) = o4;
      }
    return;
  }

  u16* out = (n0t < 1024) ? Q : K;
  const int n0 = n0t & 1023;
#pragma unroll
  for (int i = 0; i < 4; ++i)
#pragma unroll
    for (int j = 0; j < 4; ++j)
#pragma unroll
      for (int r = 0; r < 4; ++r) {
        const int m = m0 + wm * 64 + i * 16 + (l >> 4) * 4 + r;
        const int n = n0 + wn * 64 + j * 16 + (l & 15);
        out[(size_t)m * DD + n] = f2bf(acc[i][j][r]);
      }
}

// ---- kernel 2: Sc = Q K^T / 32 fp32, lower-triangular blocks only,
//      triangular-packed grid: blockIdx.x in [0,136) decodes to (mb,nb) ----
__global__ __launch_bounds__(256, 2) void scores_gemm(const u16* __restrict__ Q,
                                                      const u16* __restrict__ Kt,
                                                      float* __restrict__ Sc) {
  const int b = blockIdx.z;
  const int tcode = blockIdx.x;  // 0..135
  int mb = (int)((sqrtf(8.0f * (float)tcode + 1.0f) - 1.0f) * 0.5f);
  while ((mb + 1) * (mb + 2) / 2 <= tcode) ++mb;  // fixup fp error
  while (mb * (mb + 1) / 2 > tcode) --mb;
  const int nb = tcode - mb * (mb + 1) / 2;
  const int m0 = mb * 128, n0 = nb * 128;

  floatx4 acc[4][4];
  gemm_core_128(Q + (size_t)b * SS * DD, Kt + (size_t)b * SS * DD, DD, DD, m0, n0, DD, acc);

  float* out = Sc + (size_t)b * SS * SS;
  const int t = threadIdx.x, w = t >> 6, l = t & 63;
  const int wm = w >> 1, wn = w & 1;
#pragma unroll
  for (int i = 0; i < 4; ++i)
#pragma unroll
    for (int j = 0; j < 4; ++j)
#pragma unroll
      for (int r = 0; r < 4; ++r) {
        const int m = m0 + wm * 64 + i * 16 + (l >> 4) * 4 + r;
        const int n = n0 + wn * 64 + j * 16 + (l & 15);
        out[(size_t)m * SS + n] = acc[i][j][r] * 0.03125f;  // 1/sqrt(1024)
      }
}

// ---- kernel 3: causal row softmax, one WAVE per row, register-cached.
//      Single global read; no LDS, no block barriers. P bf16 out, rows
//      zero-filled through the 128-aligned diag-block edge. ----
__global__ __launch_bounds__(256) void softmax_causal(const float* __restrict__ Sc,
                                                      u16* __restrict__ P) {
  const int row = blockIdx.x * 4 + (threadIdx.x >> 6);  // b*2048 + i
  const int l = threadIdx.x & 63;
  const int b = row >> 11, i = row & 2047;
  const float* s = Sc + (size_t)b * SS * SS + (size_t)i * SS;
  u16* p = P + (size_t)b * SS * SS + (size_t)i * SS;
  const int n = i + 1;                      // valid columns [0, n)
  const int jend = (i + 128) & ~127;        // pv reads cols [0, jend)
  const int nc = (jend + 255) >> 8;         // 256-col chunks (1..8)

  float4 v[8];
  float mx = -INFINITY;
#pragma unroll
  for (int c = 0; c < 8; ++c) {
    if (c < nc) {
      const int col = (c * 64 + l) * 4;
      float4 a = *(const float4*)(s + col);
      a.x = (col + 0 < n) ? a.x : -INFINITY;
      a.y = (col + 1 < n) ? a.y : -INFINITY;
      a.z = (col + 2 < n) ? a.z : -INFINITY;
      a.w = (col + 3 < n) ? a.w : -INFINITY;
      v[c] = a;
      mx = fmaxf(mx, fmaxf(fmaxf(a.x, a.y), fmaxf(a.z, a.w)));
    }
  }
#pragma unroll
  for (int o = 32; o > 0; o >>= 1) mx = fmaxf(mx, __shfl_xor(mx, o, 64));

  float sum = 0.f;
#pragma unroll
  for (int c = 0; c < 8; ++c) {
    if (c < nc) {
      float4 a = v[c];
      a.x = __expf(a.x - mx);  // exp(-inf)=0 for masked lanes
      a.y = __expf(a.y - mx);
      a.z = __expf(a.z - mx);
      a.w = __expf(a.w - mx);
      v[c] = a;
      sum += (a.x + a.y) + (a.z + a.w);
    }
  }
#pragma unroll
  for (int o = 32; o > 0; o >>= 1) sum += __shfl_xor(sum, o, 64);
  const float inv = 1.0f / sum;

#pragma unroll
  for (int c = 0; c < 8; ++c) {
    if (c < nc) {
      const int col = (c * 64 + l) * 4;
      ushort4 o4;
      o4.x = f2bf(v[c].x * inv);
      o4.y = f2bf(v[c].y * inv);
      o4.z = f2bf(v[c].z * inv);
      o4.w = f2bf(v[c].w * inv);
      *(ushort4*)(p + col) = o4;
    }
  }
}

// ---- kernel 4: O = P V (causal K-range), fp32 out; longest blocks first ----
__global__ __launch_bounds__(256, 2) void pv_gemm(const u16* __restrict__ P,
                                                  const u16* __restrict__ Vt,
                                                  float* __restrict__ out) {
  const int b = blockIdx.z;
  const int mb = 15 - blockIdx.y;           // schedule kend=2048 blocks first
  const int m0 = mb * 128, n0 = blockIdx.x * 128;
  floatx4 acc[4][4];
  // rows m0..m0+127 only attend to keys k < m0+128
  gemm_core_128(P + (size_t)b * SS * SS, Vt + (size_t)b * DD * SS, SS, SS, m0, n0, m0 + 128, acc);

  float* o = out + (size_t)b * SS * DD;
  const int t = threadIdx.x, w = t >> 6, l = t & 63;
  const int wm = w >> 1, wn = w & 1;
#pragma unroll
  for (int i = 0; i < 4; ++i)
#pragma unroll
    for (int j = 0; j < 4; ++j)
#pragma unroll
      for (int r = 0; r < 4; ++r) {
        const int m = m0 + wm * 64 + i * 16 + (l >> 4) * 4 + r;
        const int n = n0 + wn * 64 + j * 16 + (l & 15);
        o[(size_t)m * DD + n] = acc[i][j][r];
      }
}

extern "C" void kernel_launch(void* const* d_in, const int* in_sizes, int n_in,
                              void* d_out, int out_size, void* d_ws, size_t ws_size,
                              hipStream_t stream) {
  const float* x  = (const float*)d_in[0];
  const float* WQ = (const float*)d_in[1];
  const float* WK = (const float*)d_in[2];
  const float* WV = (const float*)d_in[3];
  float* out = (float*)d_out;

  // workspace carve (bytes): Wt 6M | xb 16M | Q 16M | K 16M | Vt 16M | P 32M | Sc 64M
  char* ws = (char*)d_ws;
  const size_t WT_OFF = 0;
  const size_t XB_OFF = WT_OFF + (size_t)3072 * 1024 * 2;
  const size_t Q_OFF  = XB_OFF + (size_t)BB * SS * DD * 2;
  const size_t K_OFF  = Q_OFF + (size_t)BB * SS * DD * 2;
  const size_t VT_OFF = K_OFF + (size_t)BB * SS * DD * 2;
  const size_t P_OFF  = VT_OFF + (size_t)BB * SS * DD * 2;
  const size_t SC_OFF = P_OFF + (size_t)BB * SS * SS * 2;
  u16*   Wt = (u16*)(ws + WT_OFF);
  u16*   xb = (u16*)(ws + XB_OFF);
  u16*   Q  = (u16*)(ws + Q_OFF);
  u16*   Kb = (u16*)(ws + K_OFF);
  u16*   Vt = (u16*)(ws + VT_OFF);
  u16*   P  = (u16*)(ws + P_OFF);
  float* Sc = (float*)(ws + SC_OFF);

  hipLaunchKernelGGL(prep, dim3(8960), dim3(256), 0, stream, x, WQ, WK, WV, xb, Wt);
  hipLaunchKernelGGL(qkv_gemm, dim3(64, 24), dim3(256), 0, stream, xb, Wt, Q, Kb, Vt);
  hipLaunchKernelGGL(scores_gemm, dim3(136, 1, 4), dim3(256), 0, stream, Q, Kb, Sc);
  hipLaunchKernelGGL(softmax_causal, dim3(2048), dim3(256), 0, stream, Sc, P);
  hipLaunchKernelGGL(pv_gemm, dim3(8, 16, 4), dim3(256), 0, stream, P, Vt, out);
}

// Round 5
// 236.644 us; speedup vs baseline: 1.1732x; 1.1107x over previous
//
#include <hip/hip_runtime.h>
#include <stdint.h>

// SelfAttention: B=4, S=2048, D=1024, causal, single head of dim 1024.
// Inputs/outputs fp32 on device (per reference); GEMMs run bf16 MFMA with
// fp32 accumulation (no fp32-input MFMA on CDNA4).
// R5: BK=64 core with XOR-swizzled LDS chunks (kills bank conflicts that
// sank R4), bf16 score matrix (halves softmax traffic).

typedef unsigned short u16;
typedef __attribute__((ext_vector_type(8))) short shortx8;  // 8 bf16 (4 VGPRs)
typedef __attribute__((ext_vector_type(4))) float floatx4;

static constexpr int BB = 4;
static constexpr int SS = 2048;
static constexpr int DD = 1024;

__device__ __forceinline__ u16 f2bf(float f) {
  union { float f; uint32_t u; } c; c.f = f;
  uint32_t u = c.u;
  return (u16)((u + 0x7fffu + ((u >> 16) & 1u)) >> 16);  // RNE
}

__device__ __forceinline__ float bfhi2f(uint32_t u) {  // high 16 bits as bf16
  union { uint32_t u; float f; } c; c.u = u & 0xffff0000u; return c.f;
}
__device__ __forceinline__ float bflo2f(uint32_t u) {  // low 16 bits as bf16
  union { uint32_t u; float f; } c; c.u = u << 16; return c.f;
}

#define GLOAD_LDS16(g, l)                                                              \
  __builtin_amdgcn_global_load_lds((const __attribute__((address_space(1))) void*)(g), \
                                   (__attribute__((address_space(3))) void*)(l), 16, 0, 0)

// 128x128 C-tile GEMM core, BK=64, XOR-swizzled LDS:
//   logical 16B chunk c (0..7) of row r lives at physical chunk c ^ (r & 7).
//   Fragment reads hit all 8 bank groups across 8 lanes -> 2-way max (free).
//   A  [M][lda] bf16 row-major rows m0.., Bt [N][ldb] rows n0.. (B^T).
//   acc[4][4] per-wave 4x4 grid of 16x16 fp32 tiles; waves 2x2. kend % 64 == 0.
__device__ __forceinline__ void gemm_core_128(
    const u16* __restrict__ A, const u16* __restrict__ Bt,
    int lda, int ldb, int m0, int n0, int kend, floatx4 acc[4][4])
{
  __shared__ u16 lA[128 * 64];  // [row][64], physical chunks swizzled
  __shared__ u16 lB[128 * 64];
  const int t = threadIdx.x;
  const int w = t >> 6, l = t & 63;
  const int wm = w >> 1, wn = w & 1;
  const int sr = l >> 3;                          // staging row within 8-row group
  const int scq = ((l & 7) ^ (l >> 3)) * 8;       // swizzled SOURCE chunk (elems)

#pragma unroll
  for (int i = 0; i < 4; ++i)
#pragma unroll
    for (int j = 0; j < 4; ++j)
      acc[i][j] = (floatx4){0.f, 0.f, 0.f, 0.f};

  const u16* Ab = A + (size_t)m0 * lda;
  const u16* Bb = Bt + (size_t)n0 * ldb;

  for (int k0 = 0; k0 < kend; k0 += 64) {
    // stage A/B 128x64 tiles: each wave 4 groups of 8 rows per matrix.
    // lane l lands at physical (row0 + l/8, chunk l&7); source chunk is
    // (l&7)^(l>>3) so that physical = logical ^ (row&7).
#pragma unroll
    for (int i = 0; i < 4; ++i) {
      const int row = w * 32 + i * 8;
      GLOAD_LDS16(Ab + (size_t)(row + sr) * lda + k0 + scq, &lA[row * 64]);
      GLOAD_LDS16(Bb + (size_t)(row + sr) * ldb + k0 + scq, &lB[row * 64]);
    }
    __syncthreads();  // drains vmcnt before barrier -> LDS visible

#pragma unroll
    for (int ks = 0; ks < 2; ++ks) {
      // fragment row = base + (l&15) -> row&7 = l&7; logical chunk q = ks*4 + l/16
      const int ca = ((ks * 4 + (l >> 4)) ^ (l & 7)) * 8;  // physical chunk (elems)
      shortx8 af[4], bf[4];
#pragma unroll
      for (int i = 0; i < 4; ++i)
        af[i] = *(const shortx8*)&lA[(wm * 64 + i * 16 + (l & 15)) * 64 + ca];
#pragma unroll
      for (int i = 0; i < 4; ++i)
        bf[i] = *(const shortx8*)&lB[(wn * 64 + i * 16 + (l & 15)) * 64 + ca];
#pragma unroll
      for (int i = 0; i < 4; ++i)
#pragma unroll
        for (int j = 0; j < 4; ++j)
          acc[i][j] = __builtin_amdgcn_mfma_f32_16x16x32_bf16(af[i], bf[j], acc[i][j], 0, 0, 0);
    }
    __syncthreads();  // protect LDS before next stage
  }
}

// ---- kernel 0: prep = x_convert (blocks 0..8191) + wt_build (blocks 8192..8959) ----
__global__ __launch_bounds__(256) void prep(const float* __restrict__ x,
                                            const float* __restrict__ WQ,
                                            const float* __restrict__ WK,
                                            const float* __restrict__ WV,
                                            u16* __restrict__ xb,
                                            u16* __restrict__ Wt) {
  __shared__ float tile[64][65];
  const int bid = blockIdx.x;
  const int t = threadIdx.x;
  if (bid < 8192) {  // xb = bf16(x), float4-vectorized
    const size_t i = (size_t)bid * 256 + t;
    float4 v = ((const float4*)x)[i];
    ushort4 o;
    o.x = f2bf(v.x); o.y = f2bf(v.y); o.z = f2bf(v.z); o.w = f2bf(v.w);
    ((ushort4*)xb)[i] = o;
    return;
  }
  // Wt[n][k] = bf16(W[k][n]), 64x64 tiles through LDS
  const int r = bid - 8192;      // 0..767
  const int wsel = r >> 8;       // 0..2
  const int rr = r & 255;
  const int k0 = (rr >> 4) * 64, n0 = (rr & 15) * 64;
  const float* W = wsel == 0 ? WQ : (wsel == 1 ? WK : WV);
  const int tx = t & 63, ty = t >> 6;
#pragma unroll
  for (int i = 0; i < 16; ++i)
    tile[ty + i * 4][tx] = W[(size_t)(k0 + ty + i * 4) * DD + n0 + tx];
  __syncthreads();
  u16* dst = Wt + (size_t)wsel * DD * DD;
#pragma unroll
  for (int i = 0; i < 16; ++i)
    dst[(size_t)(n0 + ty + i * 4) * DD + k0 + tx] = f2bf(tile[tx][ty + i * 4]);
}

// ---- kernel 1: fused QKV projection, M=8192 N=3072 K=1024.
//      Q,K written row-major bf16; V written TRANSPOSED into Vt[b][d][s]. ----
__global__ __launch_bounds__(256, 2) void qkv_gemm(const u16* __restrict__ x,
                                                   const u16* __restrict__ Wt,
                                                   u16* __restrict__ Q,
                                                   u16* __restrict__ K,
                                                   u16* __restrict__ Vt) {
  const int m0 = blockIdx.x * 128;
  const int n0t = blockIdx.y * 128;
  floatx4 acc[4][4];
  gemm_core_128(x, Wt, DD, DD, m0, n0t, DD, acc);

  const int t = threadIdx.x, w = t >> 6, l = t & 63;
  const int wm = w >> 1, wn = w & 1;

  if (n0t >= 2048) {  // V tile: write transposed. Each lane: 4 contiguous s per (i,j).
    const int bb = m0 >> 11;
    const int s0 = (m0 & 2047) + wm * 64 + (l >> 4) * 4;
    u16* vt = Vt + (size_t)bb * DD * SS;
#pragma unroll
    for (int i = 0; i < 4; ++i)
#pragma unroll
      for (int j = 0; j < 4; ++j) {
        const int n = (n0t - 2048) + wn * 64 + j * 16 + (l & 15);
        const int s = s0 + i * 16;
        ushort4 o4;
        o4.x = f2bf(acc[i][j][0]);
        o4.y = f2bf(acc[i][j][1]);
        o4.z = f2bf(acc[i][j][2]);
        o4.w = f2bf(acc[i][j][3]);
        *(ushort4*)(vt + (size_t)n * SS + s) = o4;
      }
    return;
  }

  u16* out = (n0t < 1024) ? Q : K;
  const int n0 = n0t & 1023;
#pragma unroll
  for (int i = 0; i < 4; ++i)
#pragma unroll
    for (int j = 0; j < 4; ++j)
#pragma unroll
      for (int r = 0; r < 4; ++r) {
        const int m = m0 + wm * 64 + i * 16 + (l >> 4) * 4 + r;
        const int n = n0 + wn * 64 + j * 16 + (l & 15);
        out[(size_t)m * DD + n] = f2bf(acc[i][j][r]);
      }
}

// ---- kernel 2: Scb = bf16(Q K^T / 32), lower-triangular blocks only,
//      triangular-packed grid: blockIdx.x in [0,136) decodes to (mb,nb) ----
__global__ __launch_bounds__(256, 2) void scores_gemm(const u16* __restrict__ Q,
                                                      const u16* __restrict__ Kt,
                                                      u16* __restrict__ Scb) {
  const int b = blockIdx.z;
  const int tcode = blockIdx.x;  // 0..135
  int mb = (int)((sqrtf(8.0f * (float)tcode + 1.0f) - 1.0f) * 0.5f);
  while ((mb + 1) * (mb + 2) / 2 <= tcode) ++mb;  // fixup fp error
  while (mb * (mb + 1) / 2 > tcode) --mb;
  const int nb = tcode - mb * (mb + 1) / 2;
  const int m0 = mb * 128, n0 = nb * 128;

  floatx4 acc[4][4];
  gemm_core_128(Q + (size_t)b * SS * DD, Kt + (size_t)b * SS * DD, DD, DD, m0, n0, DD, acc);

  u16* out = Scb + (size_t)b * SS * SS;
  const int t = threadIdx.x, w = t >> 6, l = t & 63;
  const int wm = w >> 1, wn = w & 1;
#pragma unroll
  for (int i = 0; i < 4; ++i)
#pragma unroll
    for (int j = 0; j < 4; ++j)
#pragma unroll
      for (int r = 0; r < 4; ++r) {
        const int m = m0 + wm * 64 + i * 16 + (l >> 4) * 4 + r;
        const int n = n0 + wn * 64 + j * 16 + (l & 15);
        out[(size_t)m * SS + n] = f2bf(acc[i][j][r] * 0.03125f);  // 1/sqrt(1024)
      }
}

// ---- kernel 3: causal row softmax, one WAVE per row, register-cached.
//      bf16 in (Scb), bf16 out (P); single global read; no LDS/barriers. ----
__global__ __launch_bounds__(256) void softmax_causal(const u16* __restrict__ Scb,
                                                      u16* __restrict__ P) {
  const int row = blockIdx.x * 4 + (threadIdx.x >> 6);  // b*2048 + i
  const int l = threadIdx.x & 63;
  const int b = row >> 11, i = row & 2047;
  const u16* s = Scb + (size_t)b * SS * SS + (size_t)i * SS;
  u16* p = P + (size_t)b * SS * SS + (size_t)i * SS;
  const int n = i + 1;                      // valid columns [0, n)
  const int jend = (i + 128) & ~127;        // pv reads cols [0, jend)
  const int nc = (jend + 511) >> 9;         // 512-col chunks (1..4)

  float v[4][8];
  float mx = -INFINITY;
#pragma unroll
  for (int c = 0; c < 4; ++c) {
    if (c < nc) {
      const int col = c * 512 + l * 8;
      uint4 raw = *(const uint4*)(s + col);
      v[c][0] = bflo2f(raw.x); v[c][1] = bfhi2f(raw.x);
      v[c][2] = bflo2f(raw.y); v[c][3] = bfhi2f(raw.y);
      v[c][4] = bflo2f(raw.z); v[c][5] = bfhi2f(raw.z);
      v[c][6] = bflo2f(raw.w); v[c][7] = bfhi2f(raw.w);
#pragma unroll
      for (int e = 0; e < 8; ++e) {
        v[c][e] = (col + e < n) ? v[c][e] : -INFINITY;
        mx = fmaxf(mx, v[c][e]);
      }
    }
  }
#pragma unroll
  for (int o = 32; o > 0; o >>= 1) mx = fmaxf(mx, __shfl_xor(mx, o, 64));

  float sum = 0.f;
#pragma unroll
  for (int c = 0; c < 4; ++c) {
    if (c < nc) {
#pragma unroll
      for (int e = 0; e < 8; ++e) {
        v[c][e] = __expf(v[c][e] - mx);  // exp(-inf)=0 for masked cols
        sum += v[c][e];
      }
    }
  }
#pragma unroll
  for (int o = 32; o > 0; o >>= 1) sum += __shfl_xor(sum, o, 64);
  const float inv = 1.0f / sum;

#pragma unroll
  for (int c = 0; c < 4; ++c) {
    if (c < nc) {
      const int col = c * 512 + l * 8;
      if (col < jend) {  // jend % 128 == 0 -> whole 8-granule in or out
        uint4 o4;
        o4.x = (uint32_t)f2bf(v[c][0] * inv) | ((uint32_t)f2bf(v[c][1] * inv) << 16);
        o4.y = (uint32_t)f2bf(v[c][2] * inv) | ((uint32_t)f2bf(v[c][3] * inv) << 16);
        o4.z = (uint32_t)f2bf(v[c][4] * inv) | ((uint32_t)f2bf(v[c][5] * inv) << 16);
        o4.w = (uint32_t)f2bf(v[c][6] * inv) | ((uint32_t)f2bf(v[c][7] * inv) << 16);
        *(uint4*)(p + col) = o4;
      }
    }
  }
}

// ---- kernel 4: O = P V (causal K-range), fp32 out; longest blocks first ----
__global__ __launch_bounds__(256, 2) void pv_gemm(const u16* __restrict__ P,
                                                  const u16* __restrict__ Vt,
                                                  float* __restrict__ out) {
  const int b = blockIdx.z;
  const int mb = 15 - blockIdx.y;           // schedule kend=2048 blocks first
  const int m0 = mb * 128, n0 = blockIdx.x * 128;
  floatx4 acc[4][4];
  // rows m0..m0+127 only attend to keys k < m0+128
  gemm_core_128(P + (size_t)b * SS * SS, Vt + (size_t)b * DD * SS, SS, SS, m0, n0, m0 + 128, acc);

  float* o = out + (size_t)b * SS * DD;
  const int t = threadIdx.x, w = t >> 6, l = t & 63;
  const int wm = w >> 1, wn = w & 1;
#pragma unroll
  for (int i = 0; i < 4; ++i)
#pragma unroll
    for (int j = 0; j < 4; ++j)
#pragma unroll
      for (int r = 0; r < 4; ++r) {
        const int m = m0 + wm * 64 + i * 16 + (l >> 4) * 4 + r;
        const int n = n0 + wn * 64 + j * 16 + (l & 15);
        o[(size_t)m * DD + n] = acc[i][j][r];
      }
}

extern "C" void kernel_launch(void* const* d_in, const int* in_sizes, int n_in,
                              void* d_out, int out_size, void* d_ws, size_t ws_size,
                              hipStream_t stream) {
  const float* x  = (const float*)d_in[0];
  const float* WQ = (const float*)d_in[1];
  const float* WK = (const float*)d_in[2];
  const float* WV = (const float*)d_in[3];
  float* out = (float*)d_out;

  // workspace carve (bytes): Wt 6M | xb 16M | Q 16M | K 16M | Vt 16M | P 32M | Scb 32M
  char* ws = (char*)d_ws;
  const size_t WT_OFF = 0;
  const size_t XB_OFF = WT_OFF + (size_t)3072 * 1024 * 2;
  const size_t Q_OFF  = XB_OFF + (size_t)BB * SS * DD * 2;
  const size_t K_OFF  = Q_OFF + (size_t)BB * SS * DD * 2;
  const size_t VT_OFF = K_OFF + (size_t)BB * SS * DD * 2;
  const size_t P_OFF  = VT_OFF + (size_t)BB * SS * DD * 2;
  const size_t SC_OFF = P_OFF + (size_t)BB * SS * SS * 2;
  u16* Wt  = (u16*)(ws + WT_OFF);
  u16* xb  = (u16*)(ws + XB_OFF);
  u16* Q   = (u16*)(ws + Q_OFF);
  u16* Kb  = (u16*)(ws + K_OFF);
  u16* Vt  = (u16*)(ws + VT_OFF);
  u16* P   = (u16*)(ws + P_OFF);
  u16* Scb = (u16*)(ws + SC_OFF);

  hipLaunchKernelGGL(prep, dim3(8960), dim3(256), 0, stream, x, WQ, WK, WV, xb, Wt);
  hipLaunchKernelGGL(qkv_gemm, dim3(64, 24), dim3(256), 0, stream, xb, Wt, Q, Kb, Vt);
  hipLaunchKernelGGL(scores_gemm, dim3(136, 1, 4), dim3(256), 0, stream, Q, Kb, Scb);
  hipLaunchKernelGGL(softmax_causal, dim3(2048), dim3(256), 0, stream, Scb, P);
  hipLaunchKernelGGL(pv_gemm, dim3(8, 16, 4), dim3(256), 0, stream, P, Vt, out);
}